// Round 9
// baseline (403.976 us; speedup 1.0000x reference)
//
#include <hip/hip_runtime.h>
#include <hip/hip_fp16.h>
#include <math.h>

// ESN: FFT(262144) over 32 cols -> fused(proj -> chunked tanh scan -> out matmul)
//      -> IFFT, REAL part only to d_out as float32 [T,32].
//
// v10 = v9 FFT passes (packed 16-col, radix-4, unchanged) + 512-thread scan:
//  * v9 scan was VALU-issue-bound at 2 waves/SIMD (VALUBusy 51%, issue
//    accounting matches 139 us). Same LDS (75,072 B -> 2 blocks/CU) but 512
//    threads/block -> 16 waves/CU (4/SIMD) and halved per-wave serial depth:
//    Phase A 2 threads/row (r-halves), Phase C one (chunk, o-group) per wave
//    x 2 iters (all 64 lanes on output rows). Phase B unchanged on waves 0-3
//    (waves 4-7 park at the barrier; partner block fills the SIMD).

constexpr int TLEN = 262144;   // 2^18 = 512*512
constexpr int NCOL = 32;       // IN == OUT == 32 real columns
constexpr int NCOLP = 16;      // packed complex columns
constexpr int NR = 50;         // reservoir size
constexpr int SCH = 64;        // scan chunk length (4096 chunks)
constexpr int LW = 28;         // scan warmup rows (validated: absmax unchanged vs 32)
constexpr int ROWS = SCH + LW; // 92 rows per chunk buffer
constexpr int CPB = 2;         // chunks per block (grid 2048)
constexpr int LDSTR = 51;      // LDS row stride in float2 (odd -> spread banks)
constexpr float TWO_PI = 6.28318530717958647692f;

__device__ __forceinline__ unsigned rev9(unsigned x) { return __brev(x) >> 23; }

// In-LDS 512-point DIT FFT on 8 interleaved columns: 4 fused radix-4
// double-stages + 1 final radix-2 stage. lds[512][9] (row padded +1 float2),
// input bit-reversed (rev9) on load. 256 threads: cl = tid&7, bb = tid>>3.
template <int SIGN>
__device__ __forceinline__ void fft512(float2 (*lds)[9], int tid) {
  const int cl = tid & 7;
  const int bb = tid >> 3;                    // 0..31
#pragma unroll
  for (int S = 0; S < 4; ++S) {               // radix-2 stages 2S+1, 2S+2 fused
    const int h = 1 << (2 * S);               // 4^S
    const float inv4h = 1.0f / (float)(4 * h);
#pragma unroll
    for (int i = 0; i < 4; ++i) {
      const int q = bb + (i << 5);            // 4-point group id 0..127
      const int j = q & (h - 1);
      const int G = q >> (2 * S);             // q / h
      const int i0 = (G << (2 * S + 2)) + j;  // G*4h + j
      float2 a0 = lds[i0][cl];
      float2 a1 = lds[i0 + h][cl];
      float2 a2 = lds[i0 + 2 * h][cl];
      float2 a3 = lds[i0 + 3 * h][cl];
      // w' = e^{SIGN*2pi*i*j/(4h)} (stage s+1), w = w'^2 (double-angle)
      const float angp = (float)SIGN * TWO_PI * ((float)j * inv4h);
      float swp, cwp;
      __sincosf(angp, &swp, &cwp);
      const float cw = cwp * cwp - swp * swp;
      const float sw = 2.0f * cwp * swp;
      float2 t1 = make_float2(a1.x * cw - a1.y * sw, a1.x * sw + a1.y * cw);
      float2 t3 = make_float2(a3.x * cw - a3.y * sw, a3.x * sw + a3.y * cw);
      float2 u0 = make_float2(a0.x + t1.x, a0.y + t1.y);
      float2 u1 = make_float2(a0.x - t1.x, a0.y - t1.y);
      float2 u2 = make_float2(a2.x + t3.x, a2.y + t3.y);
      float2 u3 = make_float2(a2.x - t3.x, a2.y - t3.y);
      float2 r2 = make_float2(u2.x * cwp - u2.y * swp, u2.x * swp + u2.y * cwp);
      float2 r3 = make_float2(u3.x * cwp - u3.y * swp, u3.x * swp + u3.y * cwp);
      const float2 s3 = (SIGN < 0) ? make_float2(r3.y, -r3.x)   // *(-i)
                                   : make_float2(-r3.y, r3.x);  // *(+i)
      lds[i0][cl]         = make_float2(u0.x + r2.x, u0.y + r2.y);
      lds[i0 + 2 * h][cl] = make_float2(u0.x - r2.x, u0.y - r2.y);
      lds[i0 + h][cl]     = make_float2(u1.x + s3.x, u1.y + s3.y);
      lds[i0 + 3 * h][cl] = make_float2(u1.x - s3.x, u1.y - s3.y);
    }
    __syncthreads();
  }
  // final radix-2 stage (s=9): half = 256
  {
#pragma unroll
    for (int i = 0; i < 8; ++i) {
      const int j = bb + (i << 5);            // butterfly 0..255; i1 = j
      float2 a = lds[j][cl];
      float2 c = lds[j + 256][cl];
      const float ang = (float)SIGN * TWO_PI * ((float)j * (1.0f / 512.0f));
      float sw, cw;
      __sincosf(ang, &sw, &cw);
      float2 t = make_float2(c.x * cw - c.y * sw, c.x * sw + c.y * cw);
      lds[j][cl]       = make_float2(a.x + t.x, a.y + t.y);
      lds[j + 256][cl] = make_float2(a.x - t.x, a.y - t.y);
    }
    __syncthreads();
  }
}

// Pass A (packed, 16 cols): input index n = nL + 512*nH; for block nL, FFT
// over nH -> kL, twiddle e^{SIGN*2pi*i*nL*kL/T}, store at ws row (kL*512+nL).
// INMODE 0 (forward): packed float2 load from real X [T,32] -> z = x2c+i*x2c1.
// INMODE 1 (inverse): build P[k] = (Va[k]+conj(Va[N-k]))/2 + i*(Vb[k]+conj(
//   Vb[N-k]))/2 from fp16 outc [T,32]; `scale` carries 0.5/T.
// Grid (512, 2): 8 packed columns per block.
template <int SIGN, int INMODE>
__global__ __launch_bounds__(256) void fft_passA(const void* __restrict__ vin,
                                                 float2* __restrict__ out,
                                                 float scale) {
  __shared__ float2 lds[512][9];
  const int nL = blockIdx.x;
  const int cg = blockIdx.y;
  const int tid = threadIdx.x;
  const int cl = tid & 7;
  const int cglob = cg * 8 + cl;              // packed col 0..15
#pragma unroll
  for (int i = 0; i < 16; ++i) {
    const int nH = (tid >> 3) + (i << 5);
    const size_t k = (size_t)(nL + (nH << 9));
    float2 v;
    if (INMODE == 0) {
      v = ((const float2*)vin)[k * NCOLP + cglob];   // (x_{2c}, x_{2c+1})
    } else {
      const size_t m = (TLEN - k) & (TLEN - 1);      // mirror frequency
      const __half2* hin = (const __half2*)vin;
      const float2 va = __half22float2(hin[k * NCOL + 2 * cglob]);
      const float2 vb = __half22float2(hin[k * NCOL + 2 * cglob + 1]);
      const float2 wa = __half22float2(hin[m * NCOL + 2 * cglob]);
      const float2 wb = __half22float2(hin[m * NCOL + 2 * cglob + 1]);
      // P = 0.5*((va+conj(wa)) + i*(vb+conj(wb))); 0.5 folded into scale
      v = make_float2(scale * (va.x + wa.x - vb.y + wb.y),
                      scale * (va.y - wa.y + vb.x + wb.x));
    }
    lds[rev9(nH)][cl] = v;
  }
  __syncthreads();
  fft512<SIGN>(lds, tid);
#pragma unroll
  for (int i = 0; i < 16; ++i) {
    const int kL = (tid >> 3) + (i << 5);
    float2 v = lds[kL][cl];
    const float rev = (float)(nL * kL) * (1.0f / 262144.0f);  // exact (<2^24 / 2^18)
    const float ang = (float)SIGN * TWO_PI * rev;
    float sw, cw;
    __sincosf(ang, &sw, &cw);
    float2 w = make_float2(v.x * cw - v.y * sw, v.x * sw + v.y * cw);
    out[(size_t)(kL * 512 + nL) * NCOLP + cglob] = w;
  }
}

// Pass B (packed): for block kL, FFT over nL (rows kL*512+nL) -> kH.
// REALOUT=false (forward): store IN-PLACE at row (kL*512+kH) -> digit-swapped.
// REALOUT=true (inverse): lds value = (y_{2c}, y_{2c+1}) real pair -> one
//   contiguous float2 store into d_out [T,32] f32, natural order.
// Grid (512, 2): 8 packed columns per block.
template <int SIGN, bool REALOUT>
__global__ __launch_bounds__(256) void fft_passB(float2* __restrict__ buf,
                                                 float* __restrict__ rout) {
  __shared__ float2 lds[512][9];
  const int kL = blockIdx.x;
  const int cg = blockIdx.y;
  const int tid = threadIdx.x;
  const int cl = tid & 7;
  const int cglob = cg * 8 + cl;
#pragma unroll
  for (int i = 0; i < 16; ++i) {
    const int nL = (tid >> 3) + (i << 5);
    lds[rev9(nL)][cl] = buf[(size_t)(kL * 512 + nL) * NCOLP + cglob];
  }
  __syncthreads();
  fft512<SIGN>(lds, tid);
#pragma unroll
  for (int i = 0; i < 16; ++i) {
    const int kH = (tid >> 3) + (i << 5);
    if (REALOUT) {
      ((float2*)rout)[(size_t)(kL + (kH << 9)) * NCOLP + cglob] = lds[kH][cl];
    } else {
      buf[(size_t)(kL * 512 + kH) * NCOLP + cglob] = lds[kH][cl];
    }
  }
}

// s' = ctanh(p + d*s);  ctanh(x+iy) = (sinh 2x + i sin 2y)/(cosh 2x + cos 2y)
__device__ __forceinline__ void esn_step(float d, float pr, float pi,
                                         float& sr, float& si) {
  const float x = fmaf(d, sr, pr);
  const float y = fmaf(d, si, pi);
  float x2 = 2.0f * x;
  x2 = fminf(fmaxf(x2, -30.0f), 30.0f);  // fp32-saturated beyond this
  const float E = __expf(x2);
  const float Ei = __expf(-x2);
  const float sh = 0.5f * (E - Ei);
  const float ch = 0.5f * (E + Ei);
  float s2, c2;
  __sincosf(2.0f * y, &s2, &c2);
  const float inv = __builtin_amdgcn_rcpf(ch + c2);
  sr = sh * inv;
  si = s2 * inv;
}

// Fused proj -> scan -> out matmul. 512 threads (8 waves), 2 chunks per block.
// Xc is PACKED [T,16] and digit-swapped: row of freq k at ((k&511)<<9)|(k>>9).
// Phase A: 2 threads per row (r-halves [0,25)/[25,50)): task = tid < 368;
//          rowid = tid>>1 (0..183), chunk = rowid>=92. Both threads of a row
//          load the same packed row + mirror row (L1-absorbed) and unpack via
//          conjugate symmetry, then project their r-half.
// Phase B: lane-parallel scan on waves 0-3 (v7 mapping): lane<25 of wave wv
//          runs task idx = wv*25+lane over its own LDS column. Waves 4-7 park;
//          the partner resident block fills the SIMD slots.
// Phase C: wave wv -> out-group wv (o0 = wv*4, wave-uniform scalar Wout
//          loads); iter p = chunk; lane = output row. All 64 lanes active.
__global__ __launch_bounds__(512) void esn_scan_fused(
    const float2* __restrict__ Xc, const float* __restrict__ Win,
    const float* __restrict__ dvec, const float* __restrict__ Wout,
    __half2* __restrict__ outh) {
  __shared__ float2 buf[CPB][ROWS * LDSTR];  // 2*92*51*8 = 75,072 B
  const int tid = threadIdx.x;
  const int lane = tid & 63;
  const int wv = tid >> 6;                    // 0..7
  const int cbase = blockIdx.x * CPB;

  // Phase A: 2 threads per row, disjoint r-halves.
  if (tid < 2 * CPB * ROWS) {                 // 368 active
    const int rowid = tid >> 1;               // 0..183
    const int g = (rowid >= ROWS) ? 1 : 0;
    const int row = rowid - g * ROWS;
    const int r0 = (tid & 1) * 25;
    const int t = (cbase + g) * SCH - LW + row;
    float2* dst = &buf[g][row * LDSTR];
    if (t < 0) {
      for (int r = r0; r < r0 + 25; ++r) dst[r] = make_float2(0.f, 0.f);
    } else {
      const size_t xrow = (size_t)(((t & 511) << 9) | (t >> 9));  // digit-swap
      const int tm = (TLEN - t) & (TLEN - 1);                     // mirror freq
      const size_t xrowm = (size_t)(((tm & 511) << 9) | (tm >> 9));
      const float4* src = (const float4*)(Xc + xrow * NCOLP);     // 128B align
      const float4* srcm = (const float4*)(Xc + xrowm * NCOLP);
      float4 z4[8], m4[8];
#pragma unroll
      for (int i = 0; i < 8; ++i) { z4[i] = src[i]; m4[i] = srcm[i]; }
      float2 xc[NCOL];
#pragma unroll
      for (int c = 0; c < NCOLP; ++c) {
        const float zx = (c & 1) ? z4[c >> 1].z : z4[c >> 1].x;
        const float zy = (c & 1) ? z4[c >> 1].w : z4[c >> 1].y;
        const float mx = (c & 1) ? m4[c >> 1].z : m4[c >> 1].x;
        const float my = (c & 1) ? m4[c >> 1].w : m4[c >> 1].y;
        // A = (Z + conj(Zm))/2 ; B = -i(Z - conj(Zm))/2
        xc[2 * c]     = make_float2(0.5f * (zx + mx), 0.5f * (zy - my));
        xc[2 * c + 1] = make_float2(0.5f * (zy + my), 0.5f * (mx - zx));
      }
      for (int r = r0; r < r0 + 25; ++r) {
        float pr = 0.f, pi = 0.f;
#pragma unroll
        for (int c = 0; c < NCOL; ++c) {
          const float w = Win[r * NCOL + c];  // uniform -> scalar broadcast
          pr = fmaf(w, xc[c].x, pr);
          pi = fmaf(w, xc[c].y, pi);
        }
        dst[r] = make_float2(pr, pi);
      }
    }
  }
  __syncthreads();

  // Phase B: lane-parallel scalar recurrences, 25 tasks per wave, waves 0-3.
  if (wv < 4 && lane < 25) {
    const int idx = wv * 25 + lane;           // 0..99
    const int c = idx / NR;                   // chunk 0 (waves 0-1) / 1 (2-3)
    const int r = idx - c * NR;
    const float d = dvec[r];
    float2* col = &buf[c][r];                 // lane-private column
    float sr = 0.f, si = 0.f;
    float2 p0 = col[0 * LDSTR];
    float2 p1 = col[1 * LDSTR];
    float2 p2 = col[2 * LDSTR];
    for (int i = 0; i < ROWS; ++i) {
      const float2 p = p0;
      p0 = p1;
      p1 = p2;
      const int ip = (i + 3 < ROWS) ? (i + 3) : (ROWS - 1);
      p2 = col[ip * LDSTR];                   // own column: no hazard
      esn_step(d, p.x, p.y, sr, si);
      if (i >= LW) col[i * LDSTR] = make_float2(sr, si);
    }
  }
  __syncthreads();

  // Phase C: out matmul. Wave wv -> out-group wv; iter p = chunk; lane = row.
  const int o0 = __builtin_amdgcn_readfirstlane(wv) << 2;  // 0,4,...,28
#pragma unroll
  for (int p = 0; p < CPB; ++p) {
    const float2* srow = &buf[p][(LW + lane) * LDSTR];
    float ar0 = 0.f, ar1 = 0.f, ar2 = 0.f, ar3 = 0.f;
    float ai0 = 0.f, ai1 = 0.f, ai2 = 0.f, ai3 = 0.f;
    for (int r = 0; r < NR; ++r) {
      const float2 s = srow[r];
      const float w0 = Wout[(o0 + 0) * NR + r];  // uniform -> scalar loads
      const float w1 = Wout[(o0 + 1) * NR + r];
      const float w2 = Wout[(o0 + 2) * NR + r];
      const float w3 = Wout[(o0 + 3) * NR + r];
      ar0 = fmaf(w0, s.x, ar0); ai0 = fmaf(w0, s.y, ai0);
      ar1 = fmaf(w1, s.x, ar1); ai1 = fmaf(w1, s.y, ai1);
      ar2 = fmaf(w2, s.x, ar2); ai2 = fmaf(w2, s.y, ai2);
      ar3 = fmaf(w3, s.x, ar3); ai3 = fmaf(w3, s.y, ai3);
    }
    __half2* orow = &outh[((size_t)(cbase + p) * SCH + lane) * NCOL + o0];
    orow[0] = __floats2half2_rn(ar0, ai0);
    orow[1] = __floats2half2_rn(ar1, ai1);
    orow[2] = __floats2half2_rn(ar2, ai2);
    orow[3] = __floats2half2_rn(ar3, ai3);
  }
}

extern "C" void kernel_launch(void* const* d_in, const int* in_sizes, int n_in,
                              void* d_out, int out_size, void* d_ws, size_t ws_size,
                              hipStream_t stream) {
  const float* X = (const float*)d_in[0];      // [T,32] f32
  const float* Win = (const float*)d_in[1];    // [50,32] f32
  const float* dvec = (const float*)d_in[2];   // [50] f32
  const float* Wout = (const float*)d_in[3];   // [32,50] f32

  float2* Wa = (float2*)d_ws;                  // packed ws: [T,16] complex, 33.5 MB
  dim3 fgrid(512, 2);

  // 1. fwd pass A: X packed (x2c + i*x2c1) -> ws  (row kL*512+nL)
  fft_passA<-1, 0><<<fgrid, 256, 0, stream>>>(X, Wa, 1.0f);
  // 2. fwd pass B: ws in-place (packed Zc, digit-swapped)
  fft_passB<-1, false><<<fgrid, 256, 0, stream>>>(Wa, nullptr);
  // 3. fused unpack+proj+scan+out: ws -> d_out (outc, fp16 complex [T,32])
  esn_scan_fused<<<TLEN / SCH / CPB, 512, 0, stream>>>(Wa, Win, dvec, Wout,
                                                       (__half2*)d_out);
  // 4. inv pass A: d_out (fp16 outc, mirror-paired) -> ws  (0.5/T in scale)
  fft_passA<1, 1><<<fgrid, 256, 0, stream>>>(d_out, Wa, 0.5f / 262144.0f);
  // 5. inv pass B: ws -> d_out, packed real pairs, float32 [T,32]
  fft_passB<1, true><<<fgrid, 256, 0, stream>>>(Wa, (float*)d_out);

  (void)in_sizes; (void)n_in; (void)out_size; (void)ws_size;
}

// Round 10
// 305.062 us; speedup vs baseline: 1.3242x; 1.3242x over previous
//
#include <hip/hip_runtime.h>
#include <hip/hip_fp16.h>
#include <math.h>

// ESN: FFT(262144) over 32 cols -> fused(proj -> chunked tanh scan -> out matmul)
//      -> IFFT, REAL part only to d_out as float32 [T,32].
//
// v11 = v9 FFT passes (packed 16-col, radix-4, unchanged) + mirror-paired scan:
//  * X real => spectrum Hermitian => proj(N-t) = conj(proj(t)) BIT-EXACTLY
//    (Win real; unpack/fma sign symmetry preserves rounding). v9 computed
//    mirrored chunks' projections independently -- 2x redundant.
//  * Block b handles chunks {b, 4095-b}: Phase A computes proj for 121 rows
//    t in [64b-28, 64b+92] once (1 thread/row), writes buf0[j] = proj(t) and
//    buf1[120-j] = conj(proj(t)). A-work x0.66, Xc loads x0.66.
//  * Phase B byte-identical to v9 (two independent 92-row buffers).
//    Phase C identical except chunk1 output index = 4095-b.
//  * v10 lesson: 512-thr/75KB block ran 1 block/CU (occupancy unchanged,
//    scan concurrency halved, +bank conflicts). 256-thr/75KB is the proven
//    2-blocks/CU shape -- reduce work per wave, not block shape.

constexpr int TLEN = 262144;   // 2^18 = 512*512
constexpr int NCOL = 32;       // IN == OUT == 32 real columns
constexpr int NCOLP = 16;      // packed complex columns
constexpr int NR = 50;         // reservoir size
constexpr int SCH = 64;        // scan chunk length (4096 chunks)
constexpr int NCHUNK = TLEN / SCH;  // 4096
constexpr int LW = 28;         // scan warmup rows (validated: absmax unchanged vs 32)
constexpr int ROWS = SCH + LW; // 92 rows per chunk buffer
constexpr int CPB = 2;         // chunks per block (self + mirror), grid 2048
constexpr int AROWS = SCH + 2 * LW + 1;  // 121 proj rows per block pair
constexpr int LDSTR = 51;      // LDS row stride in float2 (odd -> spread banks)
constexpr float TWO_PI = 6.28318530717958647692f;

__device__ __forceinline__ unsigned rev9(unsigned x) { return __brev(x) >> 23; }

// In-LDS 512-point DIT FFT on 8 interleaved columns: 4 fused radix-4
// double-stages + 1 final radix-2 stage. lds[512][9] (row padded +1 float2),
// input bit-reversed (rev9) on load. 256 threads: cl = tid&7, bb = tid>>3.
template <int SIGN>
__device__ __forceinline__ void fft512(float2 (*lds)[9], int tid) {
  const int cl = tid & 7;
  const int bb = tid >> 3;                    // 0..31
#pragma unroll
  for (int S = 0; S < 4; ++S) {               // radix-2 stages 2S+1, 2S+2 fused
    const int h = 1 << (2 * S);               // 4^S
    const float inv4h = 1.0f / (float)(4 * h);
#pragma unroll
    for (int i = 0; i < 4; ++i) {
      const int q = bb + (i << 5);            // 4-point group id 0..127
      const int j = q & (h - 1);
      const int G = q >> (2 * S);             // q / h
      const int i0 = (G << (2 * S + 2)) + j;  // G*4h + j
      float2 a0 = lds[i0][cl];
      float2 a1 = lds[i0 + h][cl];
      float2 a2 = lds[i0 + 2 * h][cl];
      float2 a3 = lds[i0 + 3 * h][cl];
      // w' = e^{SIGN*2pi*i*j/(4h)} (stage s+1), w = w'^2 (double-angle)
      const float angp = (float)SIGN * TWO_PI * ((float)j * inv4h);
      float swp, cwp;
      __sincosf(angp, &swp, &cwp);
      const float cw = cwp * cwp - swp * swp;
      const float sw = 2.0f * cwp * swp;
      float2 t1 = make_float2(a1.x * cw - a1.y * sw, a1.x * sw + a1.y * cw);
      float2 t3 = make_float2(a3.x * cw - a3.y * sw, a3.x * sw + a3.y * cw);
      float2 u0 = make_float2(a0.x + t1.x, a0.y + t1.y);
      float2 u1 = make_float2(a0.x - t1.x, a0.y - t1.y);
      float2 u2 = make_float2(a2.x + t3.x, a2.y + t3.y);
      float2 u3 = make_float2(a2.x - t3.x, a2.y - t3.y);
      float2 r2 = make_float2(u2.x * cwp - u2.y * swp, u2.x * swp + u2.y * cwp);
      float2 r3 = make_float2(u3.x * cwp - u3.y * swp, u3.x * swp + u3.y * cwp);
      const float2 s3 = (SIGN < 0) ? make_float2(r3.y, -r3.x)   // *(-i)
                                   : make_float2(-r3.y, r3.x);  // *(+i)
      lds[i0][cl]         = make_float2(u0.x + r2.x, u0.y + r2.y);
      lds[i0 + 2 * h][cl] = make_float2(u0.x - r2.x, u0.y - r2.y);
      lds[i0 + h][cl]     = make_float2(u1.x + s3.x, u1.y + s3.y);
      lds[i0 + 3 * h][cl] = make_float2(u1.x - s3.x, u1.y - s3.y);
    }
    __syncthreads();
  }
  // final radix-2 stage (s=9): half = 256
  {
#pragma unroll
    for (int i = 0; i < 8; ++i) {
      const int j = bb + (i << 5);            // butterfly 0..255; i1 = j
      float2 a = lds[j][cl];
      float2 c = lds[j + 256][cl];
      const float ang = (float)SIGN * TWO_PI * ((float)j * (1.0f / 512.0f));
      float sw, cw;
      __sincosf(ang, &sw, &cw);
      float2 t = make_float2(c.x * cw - c.y * sw, c.x * sw + c.y * cw);
      lds[j][cl]       = make_float2(a.x + t.x, a.y + t.y);
      lds[j + 256][cl] = make_float2(a.x - t.x, a.y - t.y);
    }
    __syncthreads();
  }
}

// Pass A (packed, 16 cols): input index n = nL + 512*nH; for block nL, FFT
// over nH -> kL, twiddle e^{SIGN*2pi*i*nL*kL/T}, store at ws row (kL*512+nL).
// INMODE 0 (forward): packed float2 load from real X [T,32] -> z = x2c+i*x2c1.
// INMODE 1 (inverse): build P[k] = (Va[k]+conj(Va[N-k]))/2 + i*(Vb[k]+conj(
//   Vb[N-k]))/2 from fp16 outc [T,32]; `scale` carries 0.5/T.
// Grid (512, 2): 8 packed columns per block.
template <int SIGN, int INMODE>
__global__ __launch_bounds__(256) void fft_passA(const void* __restrict__ vin,
                                                 float2* __restrict__ out,
                                                 float scale) {
  __shared__ float2 lds[512][9];
  const int nL = blockIdx.x;
  const int cg = blockIdx.y;
  const int tid = threadIdx.x;
  const int cl = tid & 7;
  const int cglob = cg * 8 + cl;              // packed col 0..15
#pragma unroll
  for (int i = 0; i < 16; ++i) {
    const int nH = (tid >> 3) + (i << 5);
    const size_t k = (size_t)(nL + (nH << 9));
    float2 v;
    if (INMODE == 0) {
      v = ((const float2*)vin)[k * NCOLP + cglob];   // (x_{2c}, x_{2c+1})
    } else {
      const size_t m = (TLEN - k) & (TLEN - 1);      // mirror frequency
      const __half2* hin = (const __half2*)vin;
      const float2 va = __half22float2(hin[k * NCOL + 2 * cglob]);
      const float2 vb = __half22float2(hin[k * NCOL + 2 * cglob + 1]);
      const float2 wa = __half22float2(hin[m * NCOL + 2 * cglob]);
      const float2 wb = __half22float2(hin[m * NCOL + 2 * cglob + 1]);
      // P = 0.5*((va+conj(wa)) + i*(vb+conj(wb))); 0.5 folded into scale
      v = make_float2(scale * (va.x + wa.x - vb.y + wb.y),
                      scale * (va.y - wa.y + vb.x + wb.x));
    }
    lds[rev9(nH)][cl] = v;
  }
  __syncthreads();
  fft512<SIGN>(lds, tid);
#pragma unroll
  for (int i = 0; i < 16; ++i) {
    const int kL = (tid >> 3) + (i << 5);
    float2 v = lds[kL][cl];
    const float rev = (float)(nL * kL) * (1.0f / 262144.0f);  // exact (<2^24 / 2^18)
    const float ang = (float)SIGN * TWO_PI * rev;
    float sw, cw;
    __sincosf(ang, &sw, &cw);
    float2 w = make_float2(v.x * cw - v.y * sw, v.x * sw + v.y * cw);
    out[(size_t)(kL * 512 + nL) * NCOLP + cglob] = w;
  }
}

// Pass B (packed): for block kL, FFT over nL (rows kL*512+nL) -> kH.
// REALOUT=false (forward): store IN-PLACE at row (kL*512+kH) -> digit-swapped.
// REALOUT=true (inverse): lds value = (y_{2c}, y_{2c+1}) real pair -> one
//   contiguous float2 store into d_out [T,32] f32, natural order.
// Grid (512, 2): 8 packed columns per block.
template <int SIGN, bool REALOUT>
__global__ __launch_bounds__(256) void fft_passB(float2* __restrict__ buf,
                                                 float* __restrict__ rout) {
  __shared__ float2 lds[512][9];
  const int kL = blockIdx.x;
  const int cg = blockIdx.y;
  const int tid = threadIdx.x;
  const int cl = tid & 7;
  const int cglob = cg * 8 + cl;
#pragma unroll
  for (int i = 0; i < 16; ++i) {
    const int nL = (tid >> 3) + (i << 5);
    lds[rev9(nL)][cl] = buf[(size_t)(kL * 512 + nL) * NCOLP + cglob];
  }
  __syncthreads();
  fft512<SIGN>(lds, tid);
#pragma unroll
  for (int i = 0; i < 16; ++i) {
    const int kH = (tid >> 3) + (i << 5);
    if (REALOUT) {
      ((float2*)rout)[(size_t)(kL + (kH << 9)) * NCOLP + cglob] = lds[kH][cl];
    } else {
      buf[(size_t)(kL * 512 + kH) * NCOLP + cglob] = lds[kH][cl];
    }
  }
}

// s' = ctanh(p + d*s);  ctanh(x+iy) = (sinh 2x + i sin 2y)/(cosh 2x + cos 2y)
__device__ __forceinline__ void esn_step(float d, float pr, float pi,
                                         float& sr, float& si) {
  const float x = fmaf(d, sr, pr);
  const float y = fmaf(d, si, pi);
  float x2 = 2.0f * x;
  x2 = fminf(fmaxf(x2, -30.0f), 30.0f);  // fp32-saturated beyond this
  const float E = __expf(x2);
  const float Ei = __expf(-x2);
  const float sh = 0.5f * (E - Ei);
  const float ch = 0.5f * (E + Ei);
  float s2, c2;
  __sincosf(2.0f * y, &s2, &c2);
  const float inv = __builtin_amdgcn_rcpf(ch + c2);
  sr = sh * inv;
  si = s2 * inv;
}

// Fused proj -> scan -> out matmul. 256 threads (4 waves); block b handles
// chunks b and NCHUNK-1-b (mirror pair). Xc is PACKED [T,16], digit-swapped:
// row of freq k at ((k&511)<<9)|(k>>9).
// Phase A: 121 threads, one proj row each: t = 64b - 28 + tid. Unpack via
//          conjugate symmetry (rows t, N-t), project, write:
//            buf0[tid]      = proj(t)        (tid < 92)
//            buf1[120-tid]  = conj(proj(t))  (tid >= 29)   [= proj(N-t)]
// Phase B: lane-parallel scan (v7/v9): lane<25 of wave wv runs task
//          idx = wv*25+lane over its own LDS column; all 4 waves active.
// Phase C: wave wv -> out-groups {wv, wv+4}; chunk0 -> b, chunk1 -> 4095-b.
__global__ __launch_bounds__(256) void esn_scan_fused(
    const float2* __restrict__ Xc, const float* __restrict__ Win,
    const float* __restrict__ dvec, const float* __restrict__ Wout,
    __half2* __restrict__ outh) {
  __shared__ float2 buf[CPB][ROWS * LDSTR];  // 2*92*51*8 = 75,072 B
  const int tid = threadIdx.x;
  const int lane = tid & 63;
  const int wv = tid >> 6;
  const int cb = blockIdx.x;                  // 0..2047

  // Phase A: one proj row per thread; dual write (buf0 + conj into buf1).
  if (tid < AROWS) {                          // 121 active
    const int t = cb * SCH - LW + tid;
    if (t < 0) {                              // only possible for tid<28 (cb=0)
      float2* dst = &buf[0][tid * LDSTR];
      for (int r = 0; r < NR; ++r) dst[r] = make_float2(0.f, 0.f);
    } else {
      const size_t xrow = (size_t)(((t & 511) << 9) | (t >> 9));  // digit-swap
      const int tm = (TLEN - t) & (TLEN - 1);                     // mirror freq
      const size_t xrowm = (size_t)(((tm & 511) << 9) | (tm >> 9));
      const float4* src = (const float4*)(Xc + xrow * NCOLP);     // 128B align
      const float4* srcm = (const float4*)(Xc + xrowm * NCOLP);
      float4 z4[8], m4[8];
#pragma unroll
      for (int i = 0; i < 8; ++i) { z4[i] = src[i]; m4[i] = srcm[i]; }
      float2 xc[NCOL];
#pragma unroll
      for (int c = 0; c < NCOLP; ++c) {
        const float zx = (c & 1) ? z4[c >> 1].z : z4[c >> 1].x;
        const float zy = (c & 1) ? z4[c >> 1].w : z4[c >> 1].y;
        const float mx = (c & 1) ? m4[c >> 1].z : m4[c >> 1].x;
        const float my = (c & 1) ? m4[c >> 1].w : m4[c >> 1].y;
        // A = (Z + conj(Zm))/2 ; B = -i(Z - conj(Zm))/2
        xc[2 * c]     = make_float2(0.5f * (zx + mx), 0.5f * (zy - my));
        xc[2 * c + 1] = make_float2(0.5f * (zy + my), 0.5f * (mx - zx));
      }
      const bool w0 = (tid < ROWS);           // buf0 row = tid
      const bool w1 = (tid >= AROWS - ROWS);  // buf1 row = 120 - tid
      float2* d0 = &buf[0][tid * LDSTR];
      float2* d1 = &buf[1][(AROWS - 1 - tid) * LDSTR];
      for (int r = 0; r < NR; ++r) {
        float pr = 0.f, pi = 0.f;
#pragma unroll
        for (int c = 0; c < NCOL; ++c) {
          const float w = Win[r * NCOL + c];  // uniform -> scalar broadcast
          pr = fmaf(w, xc[c].x, pr);
          pi = fmaf(w, xc[c].y, pi);
        }
        if (w0) d0[r] = make_float2(pr, pi);
        if (w1) d1[r] = make_float2(pr, -pi);  // proj(N-t) = conj(proj(t))
      }
    }
  }
  __syncthreads();

  // Phase B: lane-parallel scalar recurrences, 25 tasks per wave (v7/v9).
  if (lane < 25) {
    const int idx = wv * 25 + lane;           // 0..99
    const int c = idx / NR;                   // chunk 0 (waves 0-1) / 1 (2-3)
    const int r = idx - c * NR;
    const float d = dvec[r];
    float2* col = &buf[c][r];                 // lane-private column
    float sr = 0.f, si = 0.f;
    float2 p0 = col[0 * LDSTR];
    float2 p1 = col[1 * LDSTR];
    float2 p2 = col[2 * LDSTR];
    for (int i = 0; i < ROWS; ++i) {
      const float2 p = p0;
      p0 = p1;
      p1 = p2;
      const int ip = (i + 3 < ROWS) ? (i + 3) : (ROWS - 1);
      p2 = col[ip * LDSTR];                   // own column: no hazard
      esn_step(d, p.x, p.y, sr, si);
      if (i >= LW) col[i * LDSTR] = make_float2(sr, si);
    }
  }
  __syncthreads();

  // Phase C: out matmul. Wave wv -> out-groups {wv, wv+4}; lane = output row.
  const int wvu = __builtin_amdgcn_readfirstlane(wv);
#pragma unroll
  for (int p = 0; p < 2; ++p) {
    const int o0 = (wvu + (p << 2)) << 2;     // 0,4,...,28 (wave-uniform)
    for (int c = 0; c < CPB; ++c) {
      const int cchunk = (c == 0) ? cb : (NCHUNK - 1 - cb);
      const float2* srow = &buf[c][(LW + lane) * LDSTR];
      float ar0 = 0.f, ar1 = 0.f, ar2 = 0.f, ar3 = 0.f;
      float ai0 = 0.f, ai1 = 0.f, ai2 = 0.f, ai3 = 0.f;
      for (int r = 0; r < NR; ++r) {
        const float2 s = srow[r];
        const float w0 = Wout[(o0 + 0) * NR + r];  // uniform -> scalar loads
        const float w1 = Wout[(o0 + 1) * NR + r];
        const float w2 = Wout[(o0 + 2) * NR + r];
        const float w3 = Wout[(o0 + 3) * NR + r];
        ar0 = fmaf(w0, s.x, ar0); ai0 = fmaf(w0, s.y, ai0);
        ar1 = fmaf(w1, s.x, ar1); ai1 = fmaf(w1, s.y, ai1);
        ar2 = fmaf(w2, s.x, ar2); ai2 = fmaf(w2, s.y, ai2);
        ar3 = fmaf(w3, s.x, ar3); ai3 = fmaf(w3, s.y, ai3);
      }
      __half2* orow = &outh[((size_t)cchunk * SCH + lane) * NCOL + o0];
      orow[0] = __floats2half2_rn(ar0, ai0);
      orow[1] = __floats2half2_rn(ar1, ai1);
      orow[2] = __floats2half2_rn(ar2, ai2);
      orow[3] = __floats2half2_rn(ar3, ai3);
    }
  }
}

extern "C" void kernel_launch(void* const* d_in, const int* in_sizes, int n_in,
                              void* d_out, int out_size, void* d_ws, size_t ws_size,
                              hipStream_t stream) {
  const float* X = (const float*)d_in[0];      // [T,32] f32
  const float* Win = (const float*)d_in[1];    // [50,32] f32
  const float* dvec = (const float*)d_in[2];   // [50] f32
  const float* Wout = (const float*)d_in[3];   // [32,50] f32

  float2* Wa = (float2*)d_ws;                  // packed ws: [T,16] complex, 33.5 MB
  dim3 fgrid(512, 2);

  // 1. fwd pass A: X packed (x2c + i*x2c1) -> ws  (row kL*512+nL)
  fft_passA<-1, 0><<<fgrid, 256, 0, stream>>>(X, Wa, 1.0f);
  // 2. fwd pass B: ws in-place (packed Zc, digit-swapped)
  fft_passB<-1, false><<<fgrid, 256, 0, stream>>>(Wa, nullptr);
  // 3. fused unpack+proj+scan+out: ws -> d_out (outc, fp16 complex [T,32])
  esn_scan_fused<<<NCHUNK / CPB, 256, 0, stream>>>(Wa, Win, dvec, Wout,
                                                   (__half2*)d_out);
  // 4. inv pass A: d_out (fp16 outc, mirror-paired) -> ws  (0.5/T in scale)
  fft_passA<1, 1><<<fgrid, 256, 0, stream>>>(d_out, Wa, 0.5f / 262144.0f);
  // 5. inv pass B: ws -> d_out, packed real pairs, float32 [T,32]
  fft_passB<1, true><<<fgrid, 256, 0, stream>>>(Wa, (float*)d_out);

  (void)in_sizes; (void)n_in; (void)out_size; (void)ws_size;
}

// Round 12
// 287.933 us; speedup vs baseline: 1.4030x; 1.0595x over previous
//
#include <hip/hip_runtime.h>
#include <hip/hip_fp16.h>
#include <math.h>

// ESN: FFT(262144) over 32 cols -> fused(proj -> chunked tanh scan -> out matmul)
//      -> IFFT, REAL part only to d_out as float32 [T,32].
//
// v12 = v11 (mirror-paired chunks, packed FFT) with Phase A re-balanced:
//  * v11 lesson: concentrating A's 121 rows on waves 0-1 regressed scan
//    139->163 us (VALUBusy 51->36) despite 0.66x work. Work reductions only
//    pay if per-thread critical path + wave balance improve with them.
//  * Phase A now 2 threads/row by r-halves: threads [0,121) row=tid r=[0,25),
//    threads [128,249) row=tid-128 r=[25,50). All 4 waves active, per-thread
//    A work 1600 fma (half of v9/v11). Row loads duplicated across the pair
//    (L1/L2-absorbed; HBM FETCH stays mirror-shared ~31 MB). LDS writes stay
//    at the b64 bank floor: pair-bank = (3*row + r) mod 16, full coverage.
//  * Phases B/C and all FFT passes byte-identical to v11.
//  (Round 11 bench was an infrastructure failure -- container died before
//   compile; identical source resubmitted.)

constexpr int TLEN = 262144;   // 2^18 = 512*512
constexpr int NCOL = 32;       // IN == OUT == 32 real columns
constexpr int NCOLP = 16;      // packed complex columns
constexpr int NR = 50;         // reservoir size
constexpr int SCH = 64;        // scan chunk length (4096 chunks)
constexpr int NCHUNK = TLEN / SCH;  // 4096
constexpr int LW = 28;         // scan warmup rows (validated: absmax unchanged vs 32)
constexpr int ROWS = SCH + LW; // 92 rows per chunk buffer
constexpr int CPB = 2;         // chunks per block (self + mirror), grid 2048
constexpr int AROWS = SCH + 2 * LW + 1;  // 121 proj rows per block pair
constexpr int LDSTR = 51;      // LDS row stride in float2 (odd -> spread banks)
constexpr float TWO_PI = 6.28318530717958647692f;

__device__ __forceinline__ unsigned rev9(unsigned x) { return __brev(x) >> 23; }

// In-LDS 512-point DIT FFT on 8 interleaved columns: 4 fused radix-4
// double-stages + 1 final radix-2 stage. lds[512][9] (row padded +1 float2),
// input bit-reversed (rev9) on load. 256 threads: cl = tid&7, bb = tid>>3.
template <int SIGN>
__device__ __forceinline__ void fft512(float2 (*lds)[9], int tid) {
  const int cl = tid & 7;
  const int bb = tid >> 3;                    // 0..31
#pragma unroll
  for (int S = 0; S < 4; ++S) {               // radix-2 stages 2S+1, 2S+2 fused
    const int h = 1 << (2 * S);               // 4^S
    const float inv4h = 1.0f / (float)(4 * h);
#pragma unroll
    for (int i = 0; i < 4; ++i) {
      const int q = bb + (i << 5);            // 4-point group id 0..127
      const int j = q & (h - 1);
      const int G = q >> (2 * S);             // q / h
      const int i0 = (G << (2 * S + 2)) + j;  // G*4h + j
      float2 a0 = lds[i0][cl];
      float2 a1 = lds[i0 + h][cl];
      float2 a2 = lds[i0 + 2 * h][cl];
      float2 a3 = lds[i0 + 3 * h][cl];
      // w' = e^{SIGN*2pi*i*j/(4h)} (stage s+1), w = w'^2 (double-angle)
      const float angp = (float)SIGN * TWO_PI * ((float)j * inv4h);
      float swp, cwp;
      __sincosf(angp, &swp, &cwp);
      const float cw = cwp * cwp - swp * swp;
      const float sw = 2.0f * cwp * swp;
      float2 t1 = make_float2(a1.x * cw - a1.y * sw, a1.x * sw + a1.y * cw);
      float2 t3 = make_float2(a3.x * cw - a3.y * sw, a3.x * sw + a3.y * cw);
      float2 u0 = make_float2(a0.x + t1.x, a0.y + t1.y);
      float2 u1 = make_float2(a0.x - t1.x, a0.y - t1.y);
      float2 u2 = make_float2(a2.x + t3.x, a2.y + t3.y);
      float2 u3 = make_float2(a2.x - t3.x, a2.y - t3.y);
      float2 r2 = make_float2(u2.x * cwp - u2.y * swp, u2.x * swp + u2.y * cwp);
      float2 r3 = make_float2(u3.x * cwp - u3.y * swp, u3.x * swp + u3.y * cwp);
      const float2 s3 = (SIGN < 0) ? make_float2(r3.y, -r3.x)   // *(-i)
                                   : make_float2(-r3.y, r3.x);  // *(+i)
      lds[i0][cl]         = make_float2(u0.x + r2.x, u0.y + r2.y);
      lds[i0 + 2 * h][cl] = make_float2(u0.x - r2.x, u0.y - r2.y);
      lds[i0 + h][cl]     = make_float2(u1.x + s3.x, u1.y + s3.y);
      lds[i0 + 3 * h][cl] = make_float2(u1.x - s3.x, u1.y - s3.y);
    }
    __syncthreads();
  }
  // final radix-2 stage (s=9): half = 256
  {
#pragma unroll
    for (int i = 0; i < 8; ++i) {
      const int j = bb + (i << 5);            // butterfly 0..255; i1 = j
      float2 a = lds[j][cl];
      float2 c = lds[j + 256][cl];
      const float ang = (float)SIGN * TWO_PI * ((float)j * (1.0f / 512.0f));
      float sw, cw;
      __sincosf(ang, &sw, &cw);
      float2 t = make_float2(c.x * cw - c.y * sw, c.x * sw + c.y * cw);
      lds[j][cl]       = make_float2(a.x + t.x, a.y + t.y);
      lds[j + 256][cl] = make_float2(a.x - t.x, a.y - t.y);
    }
    __syncthreads();
  }
}

// Pass A (packed, 16 cols): input index n = nL + 512*nH; for block nL, FFT
// over nH -> kL, twiddle e^{SIGN*2pi*i*nL*kL/T}, store at ws row (kL*512+nL).
// INMODE 0 (forward): packed float2 load from real X [T,32] -> z = x2c+i*x2c1.
// INMODE 1 (inverse): build P[k] = (Va[k]+conj(Va[N-k]))/2 + i*(Vb[k]+conj(
//   Vb[N-k]))/2 from fp16 outc [T,32]; `scale` carries 0.5/T.
// Grid (512, 2): 8 packed columns per block.
template <int SIGN, int INMODE>
__global__ __launch_bounds__(256) void fft_passA(const void* __restrict__ vin,
                                                 float2* __restrict__ out,
                                                 float scale) {
  __shared__ float2 lds[512][9];
  const int nL = blockIdx.x;
  const int cg = blockIdx.y;
  const int tid = threadIdx.x;
  const int cl = tid & 7;
  const int cglob = cg * 8 + cl;              // packed col 0..15
#pragma unroll
  for (int i = 0; i < 16; ++i) {
    const int nH = (tid >> 3) + (i << 5);
    const size_t k = (size_t)(nL + (nH << 9));
    float2 v;
    if (INMODE == 0) {
      v = ((const float2*)vin)[k * NCOLP + cglob];   // (x_{2c}, x_{2c+1})
    } else {
      const size_t m = (TLEN - k) & (TLEN - 1);      // mirror frequency
      const __half2* hin = (const __half2*)vin;
      const float2 va = __half22float2(hin[k * NCOL + 2 * cglob]);
      const float2 vb = __half22float2(hin[k * NCOL + 2 * cglob + 1]);
      const float2 wa = __half22float2(hin[m * NCOL + 2 * cglob]);
      const float2 wb = __half22float2(hin[m * NCOL + 2 * cglob + 1]);
      // P = 0.5*((va+conj(wa)) + i*(vb+conj(wb))); 0.5 folded into scale
      v = make_float2(scale * (va.x + wa.x - vb.y + wb.y),
                      scale * (va.y - wa.y + vb.x + wb.x));
    }
    lds[rev9(nH)][cl] = v;
  }
  __syncthreads();
  fft512<SIGN>(lds, tid);
#pragma unroll
  for (int i = 0; i < 16; ++i) {
    const int kL = (tid >> 3) + (i << 5);
    float2 v = lds[kL][cl];
    const float rev = (float)(nL * kL) * (1.0f / 262144.0f);  // exact (<2^24 / 2^18)
    const float ang = (float)SIGN * TWO_PI * rev;
    float sw, cw;
    __sincosf(ang, &sw, &cw);
    float2 w = make_float2(v.x * cw - v.y * sw, v.x * sw + v.y * cw);
    out[(size_t)(kL * 512 + nL) * NCOLP + cglob] = w;
  }
}

// Pass B (packed): for block kL, FFT over nL (rows kL*512+nL) -> kH.
// REALOUT=false (forward): store IN-PLACE at row (kL*512+kH) -> digit-swapped.
// REALOUT=true (inverse): lds value = (y_{2c}, y_{2c+1}) real pair -> one
//   contiguous float2 store into d_out [T,32] f32, natural order.
// Grid (512, 2): 8 packed columns per block.
template <int SIGN, bool REALOUT>
__global__ __launch_bounds__(256) void fft_passB(float2* __restrict__ buf,
                                                 float* __restrict__ rout) {
  __shared__ float2 lds[512][9];
  const int kL = blockIdx.x;
  const int cg = blockIdx.y;
  const int tid = threadIdx.x;
  const int cl = tid & 7;
  const int cglob = cg * 8 + cl;
#pragma unroll
  for (int i = 0; i < 16; ++i) {
    const int nL = (tid >> 3) + (i << 5);
    lds[rev9(nL)][cl] = buf[(size_t)(kL * 512 + nL) * NCOLP + cglob];
  }
  __syncthreads();
  fft512<SIGN>(lds, tid);
#pragma unroll
  for (int i = 0; i < 16; ++i) {
    const int kH = (tid >> 3) + (i << 5);
    if (REALOUT) {
      ((float2*)rout)[(size_t)(kL + (kH << 9)) * NCOLP + cglob] = lds[kH][cl];
    } else {
      buf[(size_t)(kL * 512 + kH) * NCOLP + cglob] = lds[kH][cl];
    }
  }
}

// s' = ctanh(p + d*s);  ctanh(x+iy) = (sinh 2x + i sin 2y)/(cosh 2x + cos 2y)
__device__ __forceinline__ void esn_step(float d, float pr, float pi,
                                         float& sr, float& si) {
  const float x = fmaf(d, sr, pr);
  const float y = fmaf(d, si, pi);
  float x2 = 2.0f * x;
  x2 = fminf(fmaxf(x2, -30.0f), 30.0f);  // fp32-saturated beyond this
  const float E = __expf(x2);
  const float Ei = __expf(-x2);
  const float sh = 0.5f * (E - Ei);
  const float ch = 0.5f * (E + Ei);
  float s2, c2;
  __sincosf(2.0f * y, &s2, &c2);
  const float inv = __builtin_amdgcn_rcpf(ch + c2);
  sr = sh * inv;
  si = s2 * inv;
}

// Fused proj -> scan -> out matmul. 256 threads (4 waves); block b handles
// chunks b and NCHUNK-1-b (mirror pair). Xc is PACKED [T,16], digit-swapped:
// row of freq k at ((k&511)<<9)|(k>>9).
// Phase A: 2 threads per proj row by r-halves (all 4 waves active):
//            threads [0,121):   row = tid,       r in [0,25)
//            threads [128,249): row = tid - 128, r in [25,50)
//          Each unpacks rows t, N-t via conjugate symmetry and writes:
//            buf0[row]      = proj(t)        (row < 92)
//            buf1[120-row]  = conj(proj(t))  (row >= 29)   [= proj(N-t)]
// Phase B: lane-parallel scan (v7/v9): lane<25 of wave wv runs task
//          idx = wv*25+lane over its own LDS column; all 4 waves active.
// Phase C: wave wv -> out-groups {wv, wv+4}; chunk0 -> b, chunk1 -> 4095-b.
__global__ __launch_bounds__(256) void esn_scan_fused(
    const float2* __restrict__ Xc, const float* __restrict__ Win,
    const float* __restrict__ dvec, const float* __restrict__ Wout,
    __half2* __restrict__ outh) {
  __shared__ float2 buf[CPB][ROWS * LDSTR];  // 2*92*51*8 = 75,072 B
  const int tid = threadIdx.x;
  const int lane = tid & 63;
  const int wv = tid >> 6;
  const int cb = blockIdx.x;                  // 0..2047

  // Phase A: 121 rows x 2 r-halves, dual write (buf0 + conj into buf1).
  {
    const int half = tid >> 7;                // 0: r-low, 1: r-high
    const int row = tid & 127;
    if (row < AROWS) {                        // 242 active threads
      const int r0 = half * 25;
      const int t = cb * SCH - LW + row;
      if (t < 0) {                            // only cb=0, row<28 (buf0 only)
        float2* dst = &buf[0][row * LDSTR];
        for (int r = r0; r < r0 + 25; ++r) dst[r] = make_float2(0.f, 0.f);
      } else {
        const size_t xrow = (size_t)(((t & 511) << 9) | (t >> 9));  // digit-swap
        const int tm = (TLEN - t) & (TLEN - 1);                     // mirror freq
        const size_t xrowm = (size_t)(((tm & 511) << 9) | (tm >> 9));
        const float4* src = (const float4*)(Xc + xrow * NCOLP);     // 128B align
        const float4* srcm = (const float4*)(Xc + xrowm * NCOLP);
        float4 z4[8], m4[8];
#pragma unroll
        for (int i = 0; i < 8; ++i) { z4[i] = src[i]; m4[i] = srcm[i]; }
        float2 xc[NCOL];
#pragma unroll
        for (int c = 0; c < NCOLP; ++c) {
          const float zx = (c & 1) ? z4[c >> 1].z : z4[c >> 1].x;
          const float zy = (c & 1) ? z4[c >> 1].w : z4[c >> 1].y;
          const float mx = (c & 1) ? m4[c >> 1].z : m4[c >> 1].x;
          const float my = (c & 1) ? m4[c >> 1].w : m4[c >> 1].y;
          // A = (Z + conj(Zm))/2 ; B = -i(Z - conj(Zm))/2
          xc[2 * c]     = make_float2(0.5f * (zx + mx), 0.5f * (zy - my));
          xc[2 * c + 1] = make_float2(0.5f * (zy + my), 0.5f * (mx - zx));
        }
        const bool w0 = (row < ROWS);           // buf0 row = row
        const bool w1 = (row >= AROWS - ROWS);  // buf1 row = 120 - row
        float2* d0 = &buf[0][row * LDSTR];
        float2* d1 = &buf[1][(AROWS - 1 - row) * LDSTR];
        for (int r = r0; r < r0 + 25; ++r) {
          float pr = 0.f, pi = 0.f;
#pragma unroll
          for (int c = 0; c < NCOL; ++c) {
            const float w = Win[r * NCOL + c];  // uniform -> scalar broadcast
            pr = fmaf(w, xc[c].x, pr);
            pi = fmaf(w, xc[c].y, pi);
          }
          if (w0) d0[r] = make_float2(pr, pi);
          if (w1) d1[r] = make_float2(pr, -pi);  // proj(N-t) = conj(proj(t))
        }
      }
    }
  }
  __syncthreads();

  // Phase B: lane-parallel scalar recurrences, 25 tasks per wave (v7/v9).
  if (lane < 25) {
    const int idx = wv * 25 + lane;           // 0..99
    const int c = idx / NR;                   // chunk 0 (waves 0-1) / 1 (2-3)
    const int r = idx - c * NR;
    const float d = dvec[r];
    float2* col = &buf[c][r];                 // lane-private column
    float sr = 0.f, si = 0.f;
    float2 p0 = col[0 * LDSTR];
    float2 p1 = col[1 * LDSTR];
    float2 p2 = col[2 * LDSTR];
    for (int i = 0; i < ROWS; ++i) {
      const float2 p = p0;
      p0 = p1;
      p1 = p2;
      const int ip = (i + 3 < ROWS) ? (i + 3) : (ROWS - 1);
      p2 = col[ip * LDSTR];                   // own column: no hazard
      esn_step(d, p.x, p.y, sr, si);
      if (i >= LW) col[i * LDSTR] = make_float2(sr, si);
    }
  }
  __syncthreads();

  // Phase C: out matmul. Wave wv -> out-groups {wv, wv+4}; lane = output row.
  const int wvu = __builtin_amdgcn_readfirstlane(wv);
#pragma unroll
  for (int p = 0; p < 2; ++p) {
    const int o0 = (wvu + (p << 2)) << 2;     // 0,4,...,28 (wave-uniform)
    for (int c = 0; c < CPB; ++c) {
      const int cchunk = (c == 0) ? cb : (NCHUNK - 1 - cb);
      const float2* srow = &buf[c][(LW + lane) * LDSTR];
      float ar0 = 0.f, ar1 = 0.f, ar2 = 0.f, ar3 = 0.f;
      float ai0 = 0.f, ai1 = 0.f, ai2 = 0.f, ai3 = 0.f;
      for (int r = 0; r < NR; ++r) {
        const float2 s = srow[r];
        const float w0 = Wout[(o0 + 0) * NR + r];  // uniform -> scalar loads
        const float w1 = Wout[(o0 + 1) * NR + r];
        const float w2 = Wout[(o0 + 2) * NR + r];
        const float w3 = Wout[(o0 + 3) * NR + r];
        ar0 = fmaf(w0, s.x, ar0); ai0 = fmaf(w0, s.y, ai0);
        ar1 = fmaf(w1, s.x, ar1); ai1 = fmaf(w1, s.y, ai1);
        ar2 = fmaf(w2, s.x, ar2); ai2 = fmaf(w2, s.y, ai2);
        ar3 = fmaf(w3, s.x, ar3); ai3 = fmaf(w3, s.y, ai3);
      }
      __half2* orow = &outh[((size_t)cchunk * SCH + lane) * NCOL + o0];
      orow[0] = __floats2half2_rn(ar0, ai0);
      orow[1] = __floats2half2_rn(ar1, ai1);
      orow[2] = __floats2half2_rn(ar2, ai2);
      orow[3] = __floats2half2_rn(ar3, ai3);
    }
  }
}

extern "C" void kernel_launch(void* const* d_in, const int* in_sizes, int n_in,
                              void* d_out, int out_size, void* d_ws, size_t ws_size,
                              hipStream_t stream) {
  const float* X = (const float*)d_in[0];      // [T,32] f32
  const float* Win = (const float*)d_in[1];    // [50,32] f32
  const float* dvec = (const float*)d_in[2];   // [50] f32
  const float* Wout = (const float*)d_in[3];   // [32,50] f32

  float2* Wa = (float2*)d_ws;                  // packed ws: [T,16] complex, 33.5 MB
  dim3 fgrid(512, 2);

  // 1. fwd pass A: X packed (x2c + i*x2c1) -> ws  (row kL*512+nL)
  fft_passA<-1, 0><<<fgrid, 256, 0, stream>>>(X, Wa, 1.0f);
  // 2. fwd pass B: ws in-place (packed Zc, digit-swapped)
  fft_passB<-1, false><<<fgrid, 256, 0, stream>>>(Wa, nullptr);
  // 3. fused unpack+proj+scan+out: ws -> d_out (outc, fp16 complex [T,32])
  esn_scan_fused<<<NCHUNK / CPB, 256, 0, stream>>>(Wa, Win, dvec, Wout,
                                                   (__half2*)d_out);
  // 4. inv pass A: d_out (fp16 outc, mirror-paired) -> ws  (0.5/T in scale)
  fft_passA<1, 1><<<fgrid, 256, 0, stream>>>(d_out, Wa, 0.5f / 262144.0f);
  // 5. inv pass B: ws -> d_out, packed real pairs, float32 [T,32]
  fft_passB<1, true><<<fgrid, 256, 0, stream>>>(Wa, (float*)d_out);

  (void)in_sizes; (void)n_in; (void)out_size; (void)ws_size;
}